// Round 20
// baseline (28.064 us; speedup 1.0000x reference)
//
#include <hip/hip_runtime.h>

#define WINDOW 11
#define H 512
#define W 512
#define OH 502            // H - WINDOW + 1
#define OW 502
#define NCH 3
#define BATCH 8
#define RSTRIPE 11        // one unrolled 11-pass; FIFO slot = unroll index
#define NSTRIPES 46       // 45 x 11 rows + 1 x 7 live rows (masked)
#define NGRP 5            // col groups: 4 x 118 outputs + 1 x 30 (float2 lanes)
#define GRPW 118          // output cols per full group (64 lanes * 2 - 10 halo)
#define WAVES_PER_IMG (NSTRIPES * NGRP)                 // 230
#define NWAVES (BATCH * NCH * WAVES_PER_IMG)            // 5520
#define WAVES_PER_BATCH (NCH * WAVES_PER_IMG)           // 690
#define NXCD 8
#define CHUNK (NWAVES / NXCD)                           // 690 = one batch per XCD

#define NPIX_PER_BATCH (3.0f * 502.0f * 502.0f)   // 756012

// packed 2xf32: elementwise ops compile to v_pk_{add,mul,fma}_f32 on gfx950
typedef float v2f __attribute__((ext_vector_type(2)));

// ---- gfx9 DPP inclusive wave scan (64 lanes), VALU-pipe only, 4-cyc hops ----
template <int CTRL, int RM>
__device__ __forceinline__ float scan_step(float x) {
    int s = __builtin_amdgcn_update_dpp(0, __builtin_bit_cast(int, x),
                                        CTRL, RM, 0xf, false);
    return x + __builtin_bit_cast(float, s);
}
__device__ __forceinline__ float wave_iscan(float x) {
    x = scan_step<0x111, 0xf>(x);   // row_shr:1
    x = scan_step<0x112, 0xf>(x);   // row_shr:2
    x = scan_step<0x114, 0xf>(x);   // row_shr:4
    x = scan_step<0x118, 0xf>(x);   // row_shr:8
    x = scan_step<0x142, 0xa>(x);   // row_bcast:15 -> rows 1,3
    x = scan_step<0x143, 0xc>(x);   // row_bcast:31 -> rows 2,3
    return x;
}

__global__ __launch_bounds__(64) void ssim_main(const float* __restrict__ x,
                                                const float* __restrict__ y,
                                                float* __restrict__ partials) {
    const int lane = threadIdx.x & 63;

    // XCD-chunked bijective swizzle: one batch (3 images) per XCD -> halo
    // rows shared between stripes re-read XCD-L2-locally.
    const int wg    = blockIdx.x;               // 0..5519, round-robins XCDs
    const int w_lin = (wg % NXCD) * CHUNK + wg / NXCD;

    const int img = w_lin / WAVES_PER_IMG;      // b*NCH + c
    const int rem = w_lin % WAVES_PER_IMG;
    const int grp = rem / NSTRIPES;
    const int rs  = rem % NSTRIPES;             // stripe minor -> L2-contiguous

    const int i0 = rs * RSTRIPE;
    const int i1 = min(i0 + RSTRIPE, OH);       // 11 rows; stripe 45: 7 live
    const int cstart = grp * GRPW;              // first staged/output col
    const int outw   = min(GRPW, OW - cstart);  // 118 or 30
    // clamped column pair: out-of-range lanes read real (unused) data
    const int c0 = min(cstart + 2 * lane, W - 2);
    const bool tapActive = (2 * lane < outw);

    const float* __restrict__ xc = x + (size_t)img * H * W + c0;
    const float* __restrict__ yc = y + (size_t)img * H * W + c0;

    // --- burst 1: FIFO rows i0..i0+10 AND batch-A rows i0+11..i0+15 ---
    // (i0+15 <= 510 < H: no clamps needed; 32 loads outstanding before use)
    v2f fx[11], fy[11];
    v2f axA[5], ayA[5];
#pragma unroll
    for (int r = 0; r < WINDOW; ++r) {
        fx[r] = *(const v2f*)(xc + (size_t)(i0 + r) * W);
        fy[r] = *(const v2f*)(yc + (size_t)(i0 + r) * W);
    }
#pragma unroll
    for (int k = 0; k < 5; ++k) {
        axA[k] = *(const v2f*)(xc + (size_t)(i0 + 11 + k) * W);
        ayA[k] = *(const v2f*)(yc + (size_t)(i0 + 11 + k) * W);
    }

    // init window sums from FIFO registers (covers A's latency)
    v2f Qx = 0.f, Qy = 0.f, Qz = 0.f, Qw = 0.f;
#pragma unroll
    for (int r = 0; r < WINDOW; ++r) {
        Qx += fx[r];
        Qy += fy[r];
        Qz += fx[r] * fx[r] + fy[r] * fy[r];
        Qw += fx[r] * fy[r];
    }

    // packed slide: retire FIFO slot u, absorb new row (NX, NY)
#define SLIDE(u, NX, NY) do {                                         \
        Qx += NX - fx[u];                                             \
        Qy += NY - fy[u];                                             \
        Qz += NX * NX + NY * NY - fx[u] * fx[u] - fy[u] * fy[u];      \
        Qw += NX * NY - fx[u] * fy[u];                                \
        fx[u] = NX; fy[u] = NY;                                       \
    } while (0)

    float acc = 0.f;

    // window sums via DPP scan over pair-totals T, then lane+5 fetches:
    //   We[l] = (S[l+5]-q1[l+5]) - (S[l]-T[l])    (cols 2l..2l+10)
    //   Wo[l] =  S[l+5] - S[l] + q1[l]            (cols 2l+1..2l+11)
#define COMPUTE(rowActive) do {                                               \
        float Tx = Qx.x + Qx.y, Ty = Qy.x + Qy.y;                             \
        float Tz = Qz.x + Qz.y, Tw = Qw.x + Qw.y;                             \
        float Sx = wave_iscan(Tx), Sy = wave_iscan(Ty);                       \
        float Sz = wave_iscan(Tz), Sw = wave_iscan(Tw);                       \
        int src = lane + 5;                                                   \
        float Ax = __shfl(Sx, src, 64), Ay = __shfl(Sy, src, 64);             \
        float Az = __shfl(Sz, src, 64), Aw = __shfl(Sw, src, 64);             \
        float Bx = __shfl(Qx.y, src, 64), By = __shfl(Qy.y, src, 64);         \
        float Bz = __shfl(Qz.y, src, 64), Bw = __shfl(Qw.y, src, 64);         \
        v2f Wx = {Ax - Bx - Sx + Tx, Ax - Sx + Qx.y};                         \
        v2f Wy = {Ay - By - Sy + Ty, Ay - Sy + Qy.y};                         \
        v2f Wz = {Az - Bz - Sz + Tz, Az - Sz + Qz.y};                         \
        v2f Ww = {Aw - Bw - Sw + Tw, Aw - Sw + Qw.y};                         \
        /* packed SSIM for the {even, odd} window pair */                     \
        v2f mx  = Wx * (1.0f / 121.0f);                                       \
        v2f my  = Wy * (1.0f / 121.0f);                                       \
        v2f mxy = mx * my;                                                    \
        v2f m2  = mx * mx + my * my;                                          \
        v2f cov = (Ww - 121.0f * mxy) * (1.0f / 120.0f);                      \
        v2f vv  = (Wz - 121.0f * m2)  * (1.0f / 120.0f);                      \
        v2f num = (2.0f * mxy + 1e-4f) * (2.0f * cov + 9e-4f);                \
        v2f den = (m2 + 1e-4f) * (vv + 9e-4f);                                \
        float r = num.x * __builtin_amdgcn_rcpf(den.x)                        \
                + num.y * __builtin_amdgcn_rcpf(den.y);                       \
        acc += (tapActive & (rowActive)) ? r : 0.f;                           \
    } while (0)

    COMPUTE(true);                        // output row i0 (always < OH)

    // --- burst 2: batch-B rows i0+16..i0+20 (clamped; junk rows feed only
    // masked computes). First consumed 5 computes (~900 cyc) from now. ---
    v2f axB[5], ayB[5];
#pragma unroll
    for (int k = 0; k < 5; ++k) {
        const int j = min(i0 + 16 + k, H - 1);
        axB[k] = *(const v2f*)(xc + (size_t)j * W);
        ayB[k] = *(const v2f*)(yc + (size_t)j * W);
    }

    // consume batch A: slides 0..4, computes for output rows i0+1..i0+5
#pragma unroll
    for (int u = 0; u < 5; ++u) {
        SLIDE(u, axA[u], ayA[u]);
        COMPUTE(i0 + u + 1 < i1);
    }
    // consume batch B: slides 5..9, computes for output rows i0+6..i0+10
#pragma unroll
    for (int u = 0; u < 5; ++u) {
        SLIDE(u + 5, axB[u], ayB[u]);
        COMPUTE(i0 + u + 6 < i1);
    }

    // --- per-wave reduction (fixed order, deterministic), no atomics ---
    for (int off = 32; off > 0; off >>= 1)
        acc += __shfl_down(acc, off, 64);
    if (lane == 0) partials[w_lin] = acc;   // batch-contiguous layout
}

__global__ __launch_bounds__(64) void ssim_reduce(const float* __restrict__ partials,
                                                  float* __restrict__ out) {
    const int b    = blockIdx.x;           // one wave per batch element
    const int lane = threadIdx.x & 63;
    float s = 0.f;
    for (int k = lane; k < WAVES_PER_BATCH; k += 64)   // 690, fixed order
        s += partials[b * WAVES_PER_BATCH + k];
    for (int off = 32; off > 0; off >>= 1)
        s += __shfl_down(s, off, 64);
    if (lane == 0)
        out[b] = (1.0f - s / NPIX_PER_BATCH) * 0.5f;
}

extern "C" void kernel_launch(void* const* d_in, const int* in_sizes, int n_in,
                              void* d_out, int out_size, void* d_ws, size_t ws_size,
                              hipStream_t stream) {
    const float* x = (const float*)d_in[0];
    const float* y = (const float*)d_in[1];
    float* out      = (float*)d_out;
    float* partials = (float*)d_ws;   // 5520 floats, fully overwritten each call

    ssim_main<<<NWAVES, 64, 0, stream>>>(x, y, partials);
    ssim_reduce<<<BATCH, 64, 0, stream>>>(partials, out);
}